// Round 1
// baseline (1437.029 us; speedup 1.0000x reference)
//
#include <hip/hip_runtime.h>
#include <hip/hip_bf16.h>

#define N_NODES 8192
#define F_IN    512
#define H_DIM   256
#define O_DIM   128
#define C_DIM   64
#define E_EDGES 262144

// ---------------- degree ----------------
__global__ __launch_bounds__(256) void init_deg_kernel(float* __restrict__ deg) {
    int i = blockIdx.x * 256 + threadIdx.x;
    if (i < N_NODES) deg[i] = 1.0f;  // self-loop
}

__global__ __launch_bounds__(256) void count_deg_kernel(const int* __restrict__ dst,
                                                        float* __restrict__ deg) {
    int e = blockIdx.x * 256 + threadIdx.x;
    if (e < E_EDGES) atomicAdd(&deg[dst[e]], 1.0f);
}

__global__ __launch_bounds__(256) void dinv_kernel(const float* __restrict__ deg,
                                                   float* __restrict__ dinv) {
    int i = blockIdx.x * 256 + threadIdx.x;
    if (i < N_NODES) dinv[i] = rsqrtf(deg[i]);
}

// ---------------- generic tiled fp32 GEMM: g = dinv ⊙ (A @ W); agg = g ----------------
template<int BM, int BN, int BK, int TM, int TN>
__global__ __launch_bounds__(256) void gemm_scale_kernel(
    const float* __restrict__ A, const float* __restrict__ W,
    const float* __restrict__ dinv,
    float* __restrict__ g, float* __restrict__ agg,
    int M, int N, int K)
{
    __shared__ float As[BK][BM + 4];
    __shared__ float Ws[BK][BN + 4];
    const int tid = threadIdx.x;
    constexpr int TCOLS = BN / TN;
    const int tx = tid % TCOLS;
    const int ty = tid / TCOLS;
    const int m0 = blockIdx.y * BM;
    const int n0 = blockIdx.x * BN;

    float acc[TM][TN];
#pragma unroll
    for (int m = 0; m < TM; ++m)
#pragma unroll
        for (int n = 0; n < TN; ++n) acc[m][n] = 0.0f;

    for (int k0 = 0; k0 < K; k0 += BK) {
        // A tile: BM x BK, stored transposed As[k][i]
        for (int idx = tid; idx < BM * BK; idx += 256) {
            int i = idx / BK, k = idx % BK;
            As[k][i] = A[(size_t)(m0 + i) * K + k0 + k];
        }
        // W tile: BK x BN
        for (int idx = tid; idx < BK * BN; idx += 256) {
            int k = idx / BN, n = idx % BN;
            Ws[k][n] = W[(size_t)(k0 + k) * N + n0 + n];
        }
        __syncthreads();
#pragma unroll 4
        for (int k = 0; k < BK; ++k) {
            float a[TM], w[TN];
#pragma unroll
            for (int m = 0; m < TM; ++m) a[m] = As[k][ty * TM + m];
#pragma unroll
            for (int n = 0; n < TN; ++n) w[n] = Ws[k][tx * TN + n];
#pragma unroll
            for (int m = 0; m < TM; ++m)
#pragma unroll
                for (int n = 0; n < TN; ++n) acc[m][n] += a[m] * w[n];
        }
        __syncthreads();
    }

#pragma unroll
    for (int m = 0; m < TM; ++m) {
        int row = m0 + ty * TM + m;
        float s = dinv[row];
#pragma unroll
        for (int n = 0; n < TN; ++n) {
            float v = s * acc[m][n];
            size_t o = (size_t)row * N + n0 + tx * TN + n;
            g[o] = v;
            agg[o] = v;
        }
    }
}

// ---------------- edge scatter: agg[dst] += g[src], one wave per edge ----------------
template<int FD>
__global__ __launch_bounds__(256) void scatter_kernel(
    const float* __restrict__ g, float* __restrict__ agg,
    const int* __restrict__ srcv, const int* __restrict__ dstv, int E)
{
    int wave = threadIdx.x >> 6;
    int lane = threadIdx.x & 63;
    int e = blockIdx.x * 4 + wave;
    if (e >= E) return;
    int s = srcv[e];
    int d = dstv[e];
    if constexpr (FD == 256) {
        const float4* gs = (const float4*)(g + (size_t)s * 256);
        float* ad = agg + (size_t)d * 256;
        float4 v = gs[lane];
        atomicAdd(&ad[lane * 4 + 0], v.x);
        atomicAdd(&ad[lane * 4 + 1], v.y);
        atomicAdd(&ad[lane * 4 + 2], v.z);
        atomicAdd(&ad[lane * 4 + 3], v.w);
    } else {  // FD == 128
        const float2* gs = (const float2*)(g + (size_t)s * 128);
        float* ad = agg + (size_t)d * 128;
        float2 v = gs[lane];
        atomicAdd(&ad[lane * 2 + 0], v.x);
        atomicAdd(&ad[lane * 2 + 1], v.y);
    }
}

// ---------------- finalize layer 1: h = relu(dinv*agg + b) ----------------
__global__ __launch_bounds__(256) void finalize1_kernel(
    const float* __restrict__ agg, const float* __restrict__ dinv,
    const float* __restrict__ b, float* __restrict__ h)
{
    int idx = blockIdx.x * 256 + threadIdx.x;
    if (idx >= N_NODES * H_DIM) return;
    int row = idx >> 8;
    int col = idx & 255;
    float v = dinv[row] * agg[idx] + b[col];
    h[idx] = v > 0.0f ? v : 0.0f;
}

// ---------------- finalize layer 2: z = dinv*agg + b ----------------
__global__ __launch_bounds__(256) void finalize2_kernel(
    const float* __restrict__ agg, const float* __restrict__ dinv,
    const float* __restrict__ b, float* __restrict__ z)
{
    int idx = blockIdx.x * 256 + threadIdx.x;
    if (idx >= N_NODES * O_DIM) return;
    int row = idx >> 7;
    int col = idx & 127;
    z[idx] = dinv[row] * agg[idx] + b[col];
}

// ---------------- head: mu, logvar, zr ----------------
__global__ __launch_bounds__(128) void head_kernel(
    const float* __restrict__ z,
    const float* __restrict__ Wmu, const float* __restrict__ bmu,
    const float* __restrict__ Wlv, const float* __restrict__ blv,
    const float* __restrict__ eps,
    float* __restrict__ mu_out, float* __restrict__ lv_out,
    float* __restrict__ zr)
{
    __shared__ float zs[O_DIM];
    __shared__ float mu_s[C_DIM];
    __shared__ float lv_s[C_DIM];
    int node = blockIdx.x;
    int t = threadIdx.x;
    zs[t] = z[(size_t)node * O_DIM + t];
    __syncthreads();
    int c = t & 63;
    const float* W = (t < 64) ? Wmu : Wlv;
    float acc = 0.0f;
#pragma unroll 4
    for (int k = 0; k < O_DIM; ++k) acc += zs[k] * W[k * C_DIM + c];
    if (t < 64) {
        acc += bmu[c];
        mu_out[(size_t)node * C_DIM + c] = acc;
        mu_s[c] = acc;
    } else {
        acc += blv[c];
        lv_out[(size_t)node * C_DIM + c] = acc;
        lv_s[c] = acc;
    }
    __syncthreads();
    if (t < 64) {
        float stdv = __expf(0.5f * lv_s[c]);
        zr[(size_t)node * C_DIM + c] = mu_s[c] + eps[(size_t)node * C_DIM + c] * stdv;
    }
}

// ---------------- adj = sigmoid(zr @ zr^T), 128x128 tiles, K=64 ----------------
__global__ __launch_bounds__(256) void adj_kernel(
    const float* __restrict__ zr, float* __restrict__ out)
{
    __shared__ float As[64][132];
    __shared__ float Bs[64][132];
    const int tid = threadIdx.x;
    const int tx = tid % 16;
    const int ty = tid / 16;
    const int m0 = blockIdx.y * 128;
    const int n0 = blockIdx.x * 128;

    for (int idx = tid; idx < 128 * 64; idx += 256) {
        int i = idx >> 6, k = idx & 63;
        As[k][i] = zr[(size_t)(m0 + i) * 64 + k];
        Bs[k][i] = zr[(size_t)(n0 + i) * 64 + k];
    }
    __syncthreads();

    float acc[8][8];
#pragma unroll
    for (int m = 0; m < 8; ++m)
#pragma unroll
        for (int n = 0; n < 8; ++n) acc[m][n] = 0.0f;

#pragma unroll 4
    for (int k = 0; k < 64; ++k) {
        float4 a0 = *(const float4*)&As[k][ty * 8];
        float4 a1 = *(const float4*)&As[k][ty * 8 + 4];
        float4 b0 = *(const float4*)&Bs[k][tx * 8];
        float4 b1 = *(const float4*)&Bs[k][tx * 8 + 4];
        float a[8] = {a0.x, a0.y, a0.z, a0.w, a1.x, a1.y, a1.z, a1.w};
        float b[8] = {b0.x, b0.y, b0.z, b0.w, b1.x, b1.y, b1.z, b1.w};
#pragma unroll
        for (int m = 0; m < 8; ++m)
#pragma unroll
            for (int n = 0; n < 8; ++n) acc[m][n] += a[m] * b[n];
    }

#pragma unroll
    for (int m = 0; m < 8; ++m) {
        int row = m0 + ty * 8 + m;
        float* orow = out + (size_t)row * N_NODES + n0 + tx * 8;
#pragma unroll
        for (int n = 0; n < 8; ++n) {
            float v = acc[m][n];
            orow[n] = 1.0f / (1.0f + __expf(-v));
        }
    }
}

extern "C" void kernel_launch(void* const* d_in, const int* in_sizes, int n_in,
                              void* d_out, int out_size, void* d_ws, size_t ws_size,
                              hipStream_t stream) {
    const float* x   = (const float*)d_in[0];
    const int*   ei  = (const int*)  d_in[1];
    const float* eps = (const float*)d_in[2];
    const float* W1  = (const float*)d_in[3];
    const float* b1  = (const float*)d_in[4];
    const float* W2  = (const float*)d_in[5];
    const float* b2  = (const float*)d_in[6];
    const float* Wmu = (const float*)d_in[7];
    const float* bmu = (const float*)d_in[8];
    const float* Wlv = (const float*)d_in[9];
    const float* blv = (const float*)d_in[10];
    float* out = (float*)d_out;
    float* ws  = (float*)d_ws;

    const int* srcv = ei;            // edge_index[0]
    const int* dstv = ei + E_EDGES;  // edge_index[1]

    // workspace layout (floats)
    float* deg  = ws;
    float* dinv = ws + N_NODES;
    float* g1   = ws + 2 * N_NODES;                       // 8192*256
    float* agg1 = g1 + (size_t)N_NODES * H_DIM;           // 8192*256
    float* g2   = agg1 + (size_t)N_NODES * H_DIM;         // 8192*128
    float* agg2 = g2 + (size_t)N_NODES * O_DIM;           // 8192*128
    float* zr   = agg2 + (size_t)N_NODES * O_DIM;         // 8192*64

    float* mu_out = out + (size_t)N_NODES * N_NODES;
    float* lv_out = mu_out + (size_t)N_NODES * C_DIM;

    // degree + dinv
    init_deg_kernel<<<N_NODES / 256, 256, 0, stream>>>(deg);
    count_deg_kernel<<<E_EDGES / 256, 256, 0, stream>>>(dstv, deg);
    dinv_kernel<<<N_NODES / 256, 256, 0, stream>>>(deg, dinv);

    // layer 1: g1 = dinv*(x@W1); agg1 = g1
    {
        dim3 grid(H_DIM / 64, N_NODES / 128);
        gemm_scale_kernel<128, 64, 32, 8, 4><<<grid, 256, 0, stream>>>(
            x, W1, dinv, g1, agg1, N_NODES, H_DIM, F_IN);
    }
    scatter_kernel<256><<<E_EDGES / 4, 256, 0, stream>>>(g1, agg1, srcv, dstv, E_EDGES);
    finalize1_kernel<<<N_NODES * H_DIM / 256, 256, 0, stream>>>(agg1, dinv, b1, g1); // h -> g1

    // layer 2: g2 = dinv*(h@W2); agg2 = g2
    {
        dim3 grid(O_DIM / 64, N_NODES / 64);
        gemm_scale_kernel<64, 64, 32, 4, 4><<<grid, 256, 0, stream>>>(
            g1, W2, dinv, g2, agg2, N_NODES, O_DIM, H_DIM);
    }
    scatter_kernel<128><<<E_EDGES / 4, 256, 0, stream>>>(g2, agg2, srcv, dstv, E_EDGES);
    finalize2_kernel<<<N_NODES * O_DIM / 256, 256, 0, stream>>>(agg2, dinv, b2, g2); // z -> g2

    // head
    head_kernel<<<N_NODES, 128, 0, stream>>>(g2, Wmu, bmu, Wlv, blv, eps, mu_out, lv_out, zr);

    // adjacency reconstruction
    {
        dim3 grid(N_NODES / 128, N_NODES / 128);
        adj_kernel<<<grid, 256, 0, stream>>>(zr, out);
    }
}

// Round 2
// 376.634 us; speedup vs baseline: 3.8154x; 3.8154x over previous
//
#include <hip/hip_runtime.h>
#include <hip/hip_bf16.h>

#define N_NODES 8192
#define F_IN    512
#define H_DIM   256
#define O_DIM   128
#define C_DIM   64
#define E_EDGES 262144

// ---------------- CSR build ----------------
__global__ __launch_bounds__(256) void zero_cnt_kernel(int* __restrict__ cnt) {
    int i = blockIdx.x * 256 + threadIdx.x;
    if (i < N_NODES) cnt[i] = 0;
}

__global__ __launch_bounds__(256) void hist_kernel(const int* __restrict__ dst,
                                                   int* __restrict__ cnt) {
    int e = blockIdx.x * 256 + threadIdx.x;
    if (e < E_EDGES) atomicAdd(&cnt[dst[e]], 1);
}

// single block: exclusive scan over 8192 counts; also dinv = rsqrt(cnt+1)
__global__ __launch_bounds__(1024) void scan_kernel(const int* __restrict__ cnt,
                                                    int* __restrict__ row_ptr,
                                                    int* __restrict__ cursor,
                                                    float* __restrict__ dinv) {
    __shared__ int partial[1024];
    int t = threadIdx.x;
    int base = t * 8;
    int c[8];
    int s = 0;
#pragma unroll
    for (int j = 0; j < 8; ++j) { c[j] = cnt[base + j]; s += c[j]; }
    partial[t] = s;
    __syncthreads();
    for (int off = 1; off < 1024; off <<= 1) {
        int v = 0;
        if (t >= off) v = partial[t - off];
        __syncthreads();
        if (t >= off) partial[t] += v;
        __syncthreads();
    }
    int ex = (t == 0) ? 0 : partial[t - 1];
#pragma unroll
    for (int j = 0; j < 8; ++j) {
        row_ptr[base + j] = ex;
        cursor[base + j] = ex;
        ex += c[j];
        dinv[base + j] = rsqrtf((float)c[j] + 1.0f);
    }
    if (t == 1023) row_ptr[N_NODES] = ex;
}

__global__ __launch_bounds__(256) void fill_kernel(const int* __restrict__ srcv,
                                                   const int* __restrict__ dstv,
                                                   int* __restrict__ cursor,
                                                   int* __restrict__ csr_src) {
    int e = blockIdx.x * 256 + threadIdx.x;
    if (e < E_EDGES) {
        int d = dstv[e];
        int pos = atomicAdd(&cursor[d], 1);
        csr_src[pos] = srcv[e];
    }
}

// ---------------- tiled fp32 GEMM: g = dinv ⊙ (A @ W) ----------------
template<int BM, int BN, int BK, int TM, int TN>
__global__ __launch_bounds__(256) void gemm_scale_kernel(
    const float* __restrict__ A, const float* __restrict__ W,
    const float* __restrict__ dinv,
    float* __restrict__ g,
    int M, int N, int K)
{
    __shared__ float As[BK][BM + 4];
    __shared__ float Ws[BK][BN + 4];
    const int tid = threadIdx.x;
    constexpr int TCOLS = BN / TN;
    const int tx = tid % TCOLS;
    const int ty = tid / TCOLS;
    const int m0 = blockIdx.y * BM;
    const int n0 = blockIdx.x * BN;

    float acc[TM][TN];
#pragma unroll
    for (int m = 0; m < TM; ++m)
#pragma unroll
        for (int n = 0; n < TN; ++n) acc[m][n] = 0.0f;

    for (int k0 = 0; k0 < K; k0 += BK) {
        for (int idx = tid; idx < BM * BK; idx += 256) {
            int i = idx / BK, k = idx % BK;
            As[k][i] = A[(size_t)(m0 + i) * K + k0 + k];
        }
        for (int idx = tid; idx < BK * BN; idx += 256) {
            int k = idx / BN, n = idx % BN;
            Ws[k][n] = W[(size_t)(k0 + k) * N + n0 + n];
        }
        __syncthreads();
#pragma unroll 4
        for (int k = 0; k < BK; ++k) {
            float a[TM], w[TN];
#pragma unroll
            for (int m = 0; m < TM; ++m) a[m] = As[k][ty * TM + m];
#pragma unroll
            for (int n = 0; n < TN; ++n) w[n] = Ws[k][tx * TN + n];
#pragma unroll
            for (int m = 0; m < TM; ++m)
#pragma unroll
                for (int n = 0; n < TN; ++n) acc[m][n] += a[m] * w[n];
        }
        __syncthreads();
    }

#pragma unroll
    for (int m = 0; m < TM; ++m) {
        int row = m0 + ty * TM + m;
        float s = dinv[row];
#pragma unroll
        for (int n = 0; n < TN; ++n) {
            g[(size_t)row * N + n0 + tx * TN + n] = s * acc[m][n];
        }
    }
}

// ---------------- CSR gather: out = act(dinv*(g[self] + sum g[src]) + b) ----------------
// one wave per node; FD floats per node
template<int FD, bool RELU>
__global__ __launch_bounds__(256) void gather_kernel(
    const float* __restrict__ g,
    const int* __restrict__ row_ptr, const int* __restrict__ csr_src,
    const float* __restrict__ dinv, const float* __restrict__ b,
    float* __restrict__ out)
{
    constexpr int RS4 = FD / 4;  // row stride in float4
    const int wid = threadIdx.x >> 6;
    const int lane = threadIdx.x & 63;
    const int node = blockIdx.x * 4 + wid;
    if (node >= N_NODES) return;

    const float4* G4 = (const float4*)g;
    float4 acc;
    float4 acc2;
    int lane4 = (FD == 256) ? lane : (lane & 31);
    if (FD == 128 && lane >= 32) {
        // upper half-wave idles for FD=128? No — use 2 nodes per wave instead.
    }
    // For FD==256: lane covers all 64 float4 of a row.
    // For FD==128: row has 32 float4; lanes 32..63 handle a second node.
    int my_node = node;
    if (FD == 128) {
        my_node = blockIdx.x * 8 + wid * 2 + (lane >> 5);
        if (my_node >= N_NODES) return;
    }

    const int beg = row_ptr[my_node];
    const int end = row_ptr[my_node + 1];

    acc = G4[(size_t)my_node * RS4 + lane4];  // self-loop
    acc2 = make_float4(0.f, 0.f, 0.f, 0.f);

    int e = beg;
    for (; e + 4 <= end; e += 4) {
        int s0 = csr_src[e];
        int s1 = csr_src[e + 1];
        int s2 = csr_src[e + 2];
        int s3 = csr_src[e + 3];
        float4 v0 = G4[(size_t)s0 * RS4 + lane4];
        float4 v1 = G4[(size_t)s1 * RS4 + lane4];
        float4 v2 = G4[(size_t)s2 * RS4 + lane4];
        float4 v3 = G4[(size_t)s3 * RS4 + lane4];
        acc.x += v0.x + v1.x; acc.y += v0.y + v1.y;
        acc.z += v0.z + v1.z; acc.w += v0.w + v1.w;
        acc2.x += v2.x + v3.x; acc2.y += v2.y + v3.y;
        acc2.z += v2.z + v3.z; acc2.w += v2.w + v3.w;
    }
    for (; e < end; ++e) {
        int s0 = csr_src[e];
        float4 v0 = G4[(size_t)s0 * RS4 + lane4];
        acc.x += v0.x; acc.y += v0.y; acc.z += v0.z; acc.w += v0.w;
    }
    acc.x += acc2.x; acc.y += acc2.y; acc.z += acc2.z; acc.w += acc2.w;

    float di = dinv[my_node];
    const float4 bv = ((const float4*)b)[lane4];
    float4 r;
    r.x = di * acc.x + bv.x;
    r.y = di * acc.y + bv.y;
    r.z = di * acc.z + bv.z;
    r.w = di * acc.w + bv.w;
    if (RELU) {
        r.x = r.x > 0.f ? r.x : 0.f;
        r.y = r.y > 0.f ? r.y : 0.f;
        r.z = r.z > 0.f ? r.z : 0.f;
        r.w = r.w > 0.f ? r.w : 0.f;
    }
    ((float4*)out)[(size_t)my_node * RS4 + lane4] = r;
}

// ---------------- head: mu, logvar, zr ----------------
__global__ __launch_bounds__(128) void head_kernel(
    const float* __restrict__ z,
    const float* __restrict__ Wmu, const float* __restrict__ bmu,
    const float* __restrict__ Wlv, const float* __restrict__ blv,
    const float* __restrict__ eps,
    float* __restrict__ mu_out, float* __restrict__ lv_out,
    float* __restrict__ zr)
{
    __shared__ float zs[O_DIM];
    __shared__ float mu_s[C_DIM];
    __shared__ float lv_s[C_DIM];
    int node = blockIdx.x;
    int t = threadIdx.x;
    zs[t] = z[(size_t)node * O_DIM + t];
    __syncthreads();
    int c = t & 63;
    const float* W = (t < 64) ? Wmu : Wlv;
    float acc = 0.0f;
#pragma unroll 4
    for (int k = 0; k < O_DIM; ++k) acc += zs[k] * W[k * C_DIM + c];
    if (t < 64) {
        acc += bmu[c];
        mu_out[(size_t)node * C_DIM + c] = acc;
        mu_s[c] = acc;
    } else {
        acc += blv[c];
        lv_out[(size_t)node * C_DIM + c] = acc;
        lv_s[c] = acc;
    }
    __syncthreads();
    if (t < 64) {
        float stdv = __expf(0.5f * lv_s[c]);
        zr[(size_t)node * C_DIM + c] = mu_s[c] + eps[(size_t)node * C_DIM + c] * stdv;
    }
}

// ---------------- adj = sigmoid(zr @ zr^T), 128x128 tiles, K=64 ----------------
__global__ __launch_bounds__(256) void adj_kernel(
    const float* __restrict__ zr, float* __restrict__ out)
{
    __shared__ float As[64][132];
    __shared__ float Bs[64][132];
    const int tid = threadIdx.x;
    const int tx = tid % 16;
    const int ty = tid / 16;
    const int m0 = blockIdx.y * 128;
    const int n0 = blockIdx.x * 128;

    for (int idx = tid; idx < 128 * 64; idx += 256) {
        int i = idx >> 6, k = idx & 63;
        As[k][i] = zr[(size_t)(m0 + i) * 64 + k];
        Bs[k][i] = zr[(size_t)(n0 + i) * 64 + k];
    }
    __syncthreads();

    float acc[8][8];
#pragma unroll
    for (int m = 0; m < 8; ++m)
#pragma unroll
        for (int n = 0; n < 8; ++n) acc[m][n] = 0.0f;

#pragma unroll 4
    for (int k = 0; k < 64; ++k) {
        float4 a0 = *(const float4*)&As[k][ty * 8];
        float4 a1 = *(const float4*)&As[k][ty * 8 + 4];
        float4 b0 = *(const float4*)&Bs[k][tx * 8];
        float4 b1 = *(const float4*)&Bs[k][tx * 8 + 4];
        float a[8] = {a0.x, a0.y, a0.z, a0.w, a1.x, a1.y, a1.z, a1.w};
        float b[8] = {b0.x, b0.y, b0.z, b0.w, b1.x, b1.y, b1.z, b1.w};
#pragma unroll
        for (int m = 0; m < 8; ++m)
#pragma unroll
            for (int n = 0; n < 8; ++n) acc[m][n] += a[m] * b[n];
    }

#pragma unroll
    for (int m = 0; m < 8; ++m) {
        int row = m0 + ty * 8 + m;
        float* orow = out + (size_t)row * N_NODES + n0 + tx * 8;
#pragma unroll
        for (int n = 0; n < 8; ++n) {
            float v = acc[m][n];
            orow[n] = 1.0f / (1.0f + __expf(-v));
        }
    }
}

extern "C" void kernel_launch(void* const* d_in, const int* in_sizes, int n_in,
                              void* d_out, int out_size, void* d_ws, size_t ws_size,
                              hipStream_t stream) {
    const float* x   = (const float*)d_in[0];
    const int*   ei  = (const int*)  d_in[1];
    const float* eps = (const float*)d_in[2];
    const float* W1  = (const float*)d_in[3];
    const float* b1  = (const float*)d_in[4];
    const float* W2  = (const float*)d_in[5];
    const float* b2  = (const float*)d_in[6];
    const float* Wmu = (const float*)d_in[7];
    const float* bmu = (const float*)d_in[8];
    const float* Wlv = (const float*)d_in[9];
    const float* blv = (const float*)d_in[10];
    float* out = (float*)d_out;

    const int* srcv = ei;            // edge_index[0]
    const int* dstv = ei + E_EDGES;  // edge_index[1]

    // workspace layout
    char* p = (char*)d_ws;
    int* cnt     = (int*)p;                 p += N_NODES * 4;
    int* row_ptr = (int*)p;                 p += (N_NODES + 1) * 4;
    int* cursor  = (int*)p;                 p += N_NODES * 4;
    int* csr_src = (int*)p;                 p += E_EDGES * 4;
    float* dinv  = (float*)p;               p += N_NODES * 4;
    float* g1    = (float*)p;               p += (size_t)N_NODES * H_DIM * 4;  // region A
    float* h     = (float*)p;               p += (size_t)N_NODES * H_DIM * 4;  // region B
    // after gather1, region A is reused:
    float* g2 = g1;                               // 8192*128
    float* z  = g1 + (size_t)N_NODES * O_DIM;     // 8192*128
    float* zr = h;                                // 8192*64 (region B reuse after gemm2)

    float* mu_out = out + (size_t)N_NODES * N_NODES;
    float* lv_out = mu_out + (size_t)N_NODES * C_DIM;

    // ---- CSR build + dinv ----
    zero_cnt_kernel<<<N_NODES / 256, 256, 0, stream>>>(cnt);
    hist_kernel<<<E_EDGES / 256, 256, 0, stream>>>(dstv, cnt);
    scan_kernel<<<1, 1024, 0, stream>>>(cnt, row_ptr, cursor, dinv);
    fill_kernel<<<E_EDGES / 256, 256, 0, stream>>>(srcv, dstv, cursor, csr_src);

    // ---- layer 1 ----
    {
        dim3 grid(H_DIM / 64, N_NODES / 128);
        gemm_scale_kernel<128, 64, 32, 8, 4><<<grid, 256, 0, stream>>>(
            x, W1, dinv, g1, N_NODES, H_DIM, F_IN);
    }
    gather_kernel<256, true><<<N_NODES / 4, 256, 0, stream>>>(
        g1, row_ptr, csr_src, dinv, b1, h);

    // ---- layer 2 ----
    {
        dim3 grid(O_DIM / 64, N_NODES / 64);
        gemm_scale_kernel<64, 64, 32, 4, 4><<<grid, 256, 0, stream>>>(
            h, W2, dinv, g2, N_NODES, O_DIM, H_DIM);
    }
    gather_kernel<128, false><<<N_NODES / 8, 256, 0, stream>>>(
        g2, row_ptr, csr_src, dinv, b2, z);

    // ---- head ----
    head_kernel<<<N_NODES, 128, 0, stream>>>(z, Wmu, bmu, Wlv, blv, eps, mu_out, lv_out, zr);

    // ---- adjacency reconstruction ----
    {
        dim3 grid(N_NODES / 128, N_NODES / 128);
        adj_kernel<<<grid, 256, 0, stream>>>(zr, out);
    }
}

// Round 3
// 257.054 us; speedup vs baseline: 5.5904x; 1.4652x over previous
//
#include <hip/hip_runtime.h>
#include <hip/hip_bf16.h>

#define N_NODES 8192
#define F_IN    512
#define H_DIM   256
#define O_DIM   128
#define C_DIM   64
#define E_EDGES 262144

typedef __attribute__((ext_vector_type(8))) short bf16x8;
typedef __attribute__((ext_vector_type(4))) float f32x4;

__device__ inline unsigned short f2bf(float v) {
    __hip_bfloat16 h = __float2bfloat16(v);
    return *reinterpret_cast<unsigned short*>(&h);
}
__device__ inline float bf2f(unsigned short u) {
    __hip_bfloat16 h = *reinterpret_cast<__hip_bfloat16*>(&u);
    return __bfloat162float(h);
}
__device__ inline void split2(float v, unsigned short& hi, unsigned short& lo) {
    hi = f2bf(v);
    lo = f2bf(v - bf2f(hi));
}

// ---------------- CSR build ----------------
__global__ __launch_bounds__(256) void zero_cnt_kernel(int* __restrict__ cnt) {
    int i = blockIdx.x * 256 + threadIdx.x;
    if (i < N_NODES) cnt[i] = 0;
}

__global__ __launch_bounds__(256) void hist_kernel(const int* __restrict__ dst,
                                                   int* __restrict__ cnt) {
    int e = blockIdx.x * 256 + threadIdx.x;
    if (e < E_EDGES) atomicAdd(&cnt[dst[e]], 1);
}

__global__ __launch_bounds__(1024) void scan_kernel(const int* __restrict__ cnt,
                                                    int* __restrict__ row_ptr,
                                                    int* __restrict__ cursor,
                                                    float* __restrict__ dinv) {
    __shared__ int partial[1024];
    int t = threadIdx.x;
    int base = t * 8;
    int c[8];
    int s = 0;
#pragma unroll
    for (int j = 0; j < 8; ++j) { c[j] = cnt[base + j]; s += c[j]; }
    partial[t] = s;
    __syncthreads();
    for (int off = 1; off < 1024; off <<= 1) {
        int v = 0;
        if (t >= off) v = partial[t - off];
        __syncthreads();
        if (t >= off) partial[t] += v;
        __syncthreads();
    }
    int ex = (t == 0) ? 0 : partial[t - 1];
#pragma unroll
    for (int j = 0; j < 8; ++j) {
        row_ptr[base + j] = ex;
        cursor[base + j] = ex;
        ex += c[j];
        dinv[base + j] = rsqrtf((float)c[j] + 1.0f);
    }
    if (t == 1023) row_ptr[N_NODES] = ex;
}

__global__ __launch_bounds__(256) void fill_kernel(const int* __restrict__ srcv,
                                                   const int* __restrict__ dstv,
                                                   int* __restrict__ cursor,
                                                   int* __restrict__ csr_src) {
    int e = blockIdx.x * 256 + threadIdx.x;
    if (e < E_EDGES) {
        int d = dstv[e];
        int pos = atomicAdd(&cursor[d], 1);
        csr_src[pos] = srcv[e];
    }
}

// ---------------- fp32 -> (bf16 hi, bf16 lo), elementwise, float4 ----------------
__global__ __launch_bounds__(256) void split_kernel(const float* __restrict__ in,
                                                    unsigned short* __restrict__ hi,
                                                    unsigned short* __restrict__ lo,
                                                    int n4) {
    int i = blockIdx.x * 256 + threadIdx.x;
    if (i >= n4) return;
    float4 v = ((const float4*)in)[i];
    ushort4 h, l;
    split2(v.x, h.x, l.x);
    split2(v.y, h.y, l.y);
    split2(v.z, h.z, l.z);
    split2(v.w, h.w, l.w);
    ((ushort4*)hi)[i] = h;
    ((ushort4*)lo)[i] = l;
}

// ---------------- W [K x N] fp32 -> Wt hi/lo [N x K] bf16 ----------------
__global__ __launch_bounds__(256) void split_wt_kernel(const float* __restrict__ W,
                                                       unsigned short* __restrict__ wth,
                                                       unsigned short* __restrict__ wtl,
                                                       int K, int N) {
    int idx = blockIdx.x * 256 + threadIdx.x;
    if (idx >= K * N) return;
    int k = idx / N, n = idx % N;
    unsigned short h, l;
    split2(W[idx], h, l);
    wth[n * K + k] = h;
    wtl[n * K + k] = l;
}

// ---------------- split-bf16 MFMA GEMM: out = dinv ⊙ (A @ Bt^T) ----------------
// A: [8192 x K] bf16 hi/lo, Bt: [N x K] bf16 hi/lo (i.e. B transposed), out fp32 [8192 x N]
// block = 256 thr (4 waves, 2x2), tile 128x128, wave tile 64x64.
template<int N, int K>
__global__ __launch_bounds__(256) void gemm_mfma_kernel(
    const unsigned short* __restrict__ Ah, const unsigned short* __restrict__ Al,
    const unsigned short* __restrict__ Bth, const unsigned short* __restrict__ Btl,
    const float* __restrict__ dinv, float* __restrict__ out)
{
    const int tid = threadIdx.x;
    const int lane = tid & 63;
    const int wid = tid >> 6;
    const int r = lane & 15;
    const int kg = lane >> 4;
    const int m0 = blockIdx.y * 128 + (wid >> 1) * 64;
    const int n0 = blockIdx.x * 128 + (wid & 1) * 64;

    f32x4 acc[4][4];
#pragma unroll
    for (int mi = 0; mi < 4; ++mi)
#pragma unroll
        for (int ni = 0; ni < 4; ++ni) acc[mi][ni] = (f32x4){0.f, 0.f, 0.f, 0.f};

    for (int k0 = 0; k0 < K; k0 += 32) {
        const int kof = k0 + kg * 8;
        bf16x8 ah[4], al[4], bh[4], bl[4];
#pragma unroll
        for (int mi = 0; mi < 4; ++mi) {
            size_t off = (size_t)(m0 + mi * 16 + r) * K + kof;
            ah[mi] = *(const bf16x8*)(Ah + off);
            al[mi] = *(const bf16x8*)(Al + off);
        }
#pragma unroll
        for (int ni = 0; ni < 4; ++ni) {
            size_t off = (size_t)(n0 + ni * 16 + r) * K + kof;
            bh[ni] = *(const bf16x8*)(Bth + off);
            bl[ni] = *(const bf16x8*)(Btl + off);
        }
#pragma unroll
        for (int mi = 0; mi < 4; ++mi)
#pragma unroll
            for (int ni = 0; ni < 4; ++ni) {
                acc[mi][ni] = __builtin_amdgcn_mfma_f32_16x16x32_bf16(ah[mi], bh[ni], acc[mi][ni], 0, 0, 0);
                acc[mi][ni] = __builtin_amdgcn_mfma_f32_16x16x32_bf16(ah[mi], bl[ni], acc[mi][ni], 0, 0, 0);
                acc[mi][ni] = __builtin_amdgcn_mfma_f32_16x16x32_bf16(al[mi], bh[ni], acc[mi][ni], 0, 0, 0);
            }
    }

#pragma unroll
    for (int mi = 0; mi < 4; ++mi) {
        int rowb = m0 + mi * 16 + kg * 4;
        float di[4];
#pragma unroll
        for (int i = 0; i < 4; ++i) di[i] = dinv[rowb + i];
#pragma unroll
        for (int ni = 0; ni < 4; ++ni) {
            int col = n0 + ni * 16 + r;
#pragma unroll
            for (int i = 0; i < 4; ++i)
                out[(size_t)(rowb + i) * N + col] = di[i] * acc[mi][ni][i];
        }
    }
}

// ---------------- CSR gather fp32 ----------------
// FD=128 variant: 2 nodes per wave; out = dinv*(g[self] + sum g[src]) + b
__global__ __launch_bounds__(256) void gather128_kernel(
    const float* __restrict__ g,
    const int* __restrict__ row_ptr, const int* __restrict__ csr_src,
    const float* __restrict__ dinv, const float* __restrict__ b,
    float* __restrict__ out)
{
    const int wid = threadIdx.x >> 6;
    const int lane = threadIdx.x & 63;
    const int lane4 = lane & 31;
    const int my_node = blockIdx.x * 8 + wid * 2 + (lane >> 5);
    if (my_node >= N_NODES) return;

    const float4* G4 = (const float4*)g;
    const int beg = row_ptr[my_node];
    const int end = row_ptr[my_node + 1];

    float4 acc = G4[(size_t)my_node * 32 + lane4];
    float4 acc2 = make_float4(0.f, 0.f, 0.f, 0.f);

    int e = beg;
    for (; e + 4 <= end; e += 4) {
        int s0 = csr_src[e], s1 = csr_src[e + 1], s2 = csr_src[e + 2], s3 = csr_src[e + 3];
        float4 v0 = G4[(size_t)s0 * 32 + lane4];
        float4 v1 = G4[(size_t)s1 * 32 + lane4];
        float4 v2 = G4[(size_t)s2 * 32 + lane4];
        float4 v3 = G4[(size_t)s3 * 32 + lane4];
        acc.x += v0.x + v1.x; acc.y += v0.y + v1.y;
        acc.z += v0.z + v1.z; acc.w += v0.w + v1.w;
        acc2.x += v2.x + v3.x; acc2.y += v2.y + v3.y;
        acc2.z += v2.z + v3.z; acc2.w += v2.w + v3.w;
    }
    for (; e < end; ++e) {
        float4 v0 = G4[(size_t)csr_src[e] * 32 + lane4];
        acc.x += v0.x; acc.y += v0.y; acc.z += v0.z; acc.w += v0.w;
    }
    acc.x += acc2.x; acc.y += acc2.y; acc.z += acc2.z; acc.w += acc2.w;

    float di = dinv[my_node];
    const float4 bv = ((const float4*)b)[lane4];
    float4 rr;
    rr.x = di * acc.x + bv.x;
    rr.y = di * acc.y + bv.y;
    rr.z = di * acc.z + bv.z;
    rr.w = di * acc.w + bv.w;
    ((float4*)out)[(size_t)my_node * 32 + lane4] = rr;
}

// FD=256 variant: 1 node per wave; relu; writes bf16 hi/lo split
__global__ __launch_bounds__(256) void gather256_split_kernel(
    const float* __restrict__ g,
    const int* __restrict__ row_ptr, const int* __restrict__ csr_src,
    const float* __restrict__ dinv, const float* __restrict__ b,
    unsigned short* __restrict__ hh, unsigned short* __restrict__ hl)
{
    const int wid = threadIdx.x >> 6;
    const int lane = threadIdx.x & 63;
    const int my_node = blockIdx.x * 4 + wid;
    if (my_node >= N_NODES) return;

    const float4* G4 = (const float4*)g;
    const int beg = row_ptr[my_node];
    const int end = row_ptr[my_node + 1];

    float4 acc = G4[(size_t)my_node * 64 + lane];
    float4 acc2 = make_float4(0.f, 0.f, 0.f, 0.f);

    int e = beg;
    for (; e + 4 <= end; e += 4) {
        int s0 = csr_src[e], s1 = csr_src[e + 1], s2 = csr_src[e + 2], s3 = csr_src[e + 3];
        float4 v0 = G4[(size_t)s0 * 64 + lane];
        float4 v1 = G4[(size_t)s1 * 64 + lane];
        float4 v2 = G4[(size_t)s2 * 64 + lane];
        float4 v3 = G4[(size_t)s3 * 64 + lane];
        acc.x += v0.x + v1.x; acc.y += v0.y + v1.y;
        acc.z += v0.z + v1.z; acc.w += v0.w + v1.w;
        acc2.x += v2.x + v3.x; acc2.y += v2.y + v3.y;
        acc2.z += v2.z + v3.z; acc2.w += v2.w + v3.w;
    }
    for (; e < end; ++e) {
        float4 v0 = G4[(size_t)csr_src[e] * 64 + lane];
        acc.x += v0.x; acc.y += v0.y; acc.z += v0.z; acc.w += v0.w;
    }
    acc.x += acc2.x; acc.y += acc2.y; acc.z += acc2.z; acc.w += acc2.w;

    float di = dinv[my_node];
    const float4 bv = ((const float4*)b)[lane];
    float4 rr;
    rr.x = di * acc.x + bv.x;
    rr.y = di * acc.y + bv.y;
    rr.z = di * acc.z + bv.z;
    rr.w = di * acc.w + bv.w;
    rr.x = rr.x > 0.f ? rr.x : 0.f;
    rr.y = rr.y > 0.f ? rr.y : 0.f;
    rr.z = rr.z > 0.f ? rr.z : 0.f;
    rr.w = rr.w > 0.f ? rr.w : 0.f;

    ushort4 h, l;
    split2(rr.x, h.x, l.x);
    split2(rr.y, h.y, l.y);
    split2(rr.z, h.z, l.z);
    split2(rr.w, h.w, l.w);
    ((ushort4*)hh)[(size_t)my_node * 64 + lane] = h;
    ((ushort4*)hl)[(size_t)my_node * 64 + lane] = l;
}

// ---------------- head: mu, logvar, zr (fp32 out + bf16 hi/lo zr) ----------------
__global__ __launch_bounds__(128) void head_kernel(
    const float* __restrict__ z,
    const float* __restrict__ Wmu, const float* __restrict__ bmu,
    const float* __restrict__ Wlv, const float* __restrict__ blv,
    const float* __restrict__ eps,
    float* __restrict__ mu_out, float* __restrict__ lv_out,
    unsigned short* __restrict__ zrh, unsigned short* __restrict__ zrl)
{
    __shared__ float zs[O_DIM];
    __shared__ float mu_s[C_DIM];
    __shared__ float lv_s[C_DIM];
    int node = blockIdx.x;
    int t = threadIdx.x;
    zs[t] = z[(size_t)node * O_DIM + t];
    __syncthreads();
    int c = t & 63;
    const float* W = (t < 64) ? Wmu : Wlv;
    float acc = 0.0f;
#pragma unroll 4
    for (int k = 0; k < O_DIM; ++k) acc += zs[k] * W[k * C_DIM + c];
    if (t < 64) {
        acc += bmu[c];
        mu_out[(size_t)node * C_DIM + c] = acc;
        mu_s[c] = acc;
    } else {
        acc += blv[c];
        lv_out[(size_t)node * C_DIM + c] = acc;
        lv_s[c] = acc;
    }
    __syncthreads();
    if (t < 64) {
        float stdv = __expf(0.5f * lv_s[c]);
        float v = mu_s[c] + eps[(size_t)node * C_DIM + c] * stdv;
        unsigned short h, l;
        split2(v, h, l);
        zrh[(size_t)node * C_DIM + c] = h;
        zrl[(size_t)node * C_DIM + c] = l;
    }
}

// ---------------- adj = sigmoid(zr @ zr^T) via split-bf16 MFMA ----------------
// K=64; fragments straight from global (zr hi/lo ~4 MB total, L2-resident).
__global__ __launch_bounds__(256) void adj_mfma_kernel(
    const unsigned short* __restrict__ Zh, const unsigned short* __restrict__ Zl,
    float* __restrict__ out)
{
    const int tid = threadIdx.x;
    const int lane = tid & 63;
    const int wid = tid >> 6;
    const int r = lane & 15;
    const int kg = lane >> 4;
    const int m0 = blockIdx.y * 128 + (wid >> 1) * 64;
    const int n0 = blockIdx.x * 128 + (wid & 1) * 64;

    bf16x8 ah[4][2], al[4][2];
#pragma unroll
    for (int mi = 0; mi < 4; ++mi)
#pragma unroll
        for (int ks = 0; ks < 2; ++ks) {
            size_t off = (size_t)(m0 + mi * 16 + r) * C_DIM + ks * 32 + kg * 8;
            ah[mi][ks] = *(const bf16x8*)(Zh + off);
            al[mi][ks] = *(const bf16x8*)(Zl + off);
        }

    f32x4 acc[4][4];
#pragma unroll
    for (int mi = 0; mi < 4; ++mi)
#pragma unroll
        for (int ni = 0; ni < 4; ++ni) acc[mi][ni] = (f32x4){0.f, 0.f, 0.f, 0.f};

#pragma unroll
    for (int ni = 0; ni < 4; ++ni) {
        bf16x8 bh[2], bl[2];
#pragma unroll
        for (int ks = 0; ks < 2; ++ks) {
            size_t off = (size_t)(n0 + ni * 16 + r) * C_DIM + ks * 32 + kg * 8;
            bh[ks] = *(const bf16x8*)(Zh + off);
            bl[ks] = *(const bf16x8*)(Zl + off);
        }
#pragma unroll
        for (int mi = 0; mi < 4; ++mi)
#pragma unroll
            for (int ks = 0; ks < 2; ++ks) {
                acc[mi][ni] = __builtin_amdgcn_mfma_f32_16x16x32_bf16(ah[mi][ks], bh[ks], acc[mi][ni], 0, 0, 0);
                acc[mi][ni] = __builtin_amdgcn_mfma_f32_16x16x32_bf16(ah[mi][ks], bl[ks], acc[mi][ni], 0, 0, 0);
                acc[mi][ni] = __builtin_amdgcn_mfma_f32_16x16x32_bf16(al[mi][ks], bh[ks], acc[mi][ni], 0, 0, 0);
            }
    }

#pragma unroll
    for (int mi = 0; mi < 4; ++mi) {
        int rowb = m0 + mi * 16 + kg * 4;
#pragma unroll
        for (int ni = 0; ni < 4; ++ni) {
            int col = n0 + ni * 16 + r;
#pragma unroll
            for (int i = 0; i < 4; ++i) {
                float v = acc[mi][ni][i];
                float e = __expf(-v);
                out[(size_t)(rowb + i) * N_NODES + col] = 1.0f / (1.0f + e);
            }
        }
    }
}

extern "C" void kernel_launch(void* const* d_in, const int* in_sizes, int n_in,
                              void* d_out, int out_size, void* d_ws, size_t ws_size,
                              hipStream_t stream) {
    const float* x   = (const float*)d_in[0];
    const int*   ei  = (const int*)  d_in[1];
    const float* eps = (const float*)d_in[2];
    const float* W1  = (const float*)d_in[3];
    const float* b1  = (const float*)d_in[4];
    const float* W2  = (const float*)d_in[5];
    const float* b2  = (const float*)d_in[6];
    const float* Wmu = (const float*)d_in[7];
    const float* bmu = (const float*)d_in[8];
    const float* Wlv = (const float*)d_in[9];
    const float* blv = (const float*)d_in[10];
    float* out = (float*)d_out;

    const int* srcv = ei;            // edge_index[0]
    const int* dstv = ei + E_EDGES;  // edge_index[1]

    // workspace carving, 256B-aligned chunks
    char* p = (char*)d_ws;
    auto carve = [&](size_t bytes) -> void* {
        void* q = (void*)p;
        p += (bytes + 255) & ~(size_t)255;
        return q;
    };
    int* cnt      = (int*)carve(N_NODES * 4);
    int* row_ptr  = (int*)carve((N_NODES + 1) * 4);
    int* cursor   = (int*)carve(N_NODES * 4);
    int* csr_src  = (int*)carve(E_EDGES * 4);
    float* dinv   = (float*)carve(N_NODES * 4);
    unsigned short* xh   = (unsigned short*)carve((size_t)N_NODES * F_IN * 2);
    unsigned short* xl   = (unsigned short*)carve((size_t)N_NODES * F_IN * 2);
    unsigned short* w1th = (unsigned short*)carve((size_t)F_IN * H_DIM * 2);
    unsigned short* w1tl = (unsigned short*)carve((size_t)F_IN * H_DIM * 2);
    unsigned short* w2th = (unsigned short*)carve((size_t)H_DIM * O_DIM * 2);
    unsigned short* w2tl = (unsigned short*)carve((size_t)H_DIM * O_DIM * 2);
    float* g1     = (float*)carve((size_t)N_NODES * H_DIM * 4);
    unsigned short* hh   = (unsigned short*)carve((size_t)N_NODES * H_DIM * 2);
    unsigned short* hl   = (unsigned short*)carve((size_t)N_NODES * H_DIM * 2);
    float* g2     = (float*)carve((size_t)N_NODES * O_DIM * 4);
    float* z      = (float*)carve((size_t)N_NODES * O_DIM * 4);
    unsigned short* zrh  = (unsigned short*)carve((size_t)N_NODES * C_DIM * 2);
    unsigned short* zrl  = (unsigned short*)carve((size_t)N_NODES * C_DIM * 2);

    float* mu_out = out + (size_t)N_NODES * N_NODES;
    float* lv_out = mu_out + (size_t)N_NODES * C_DIM;

    // ---- CSR build + dinv ----
    zero_cnt_kernel<<<N_NODES / 256, 256, 0, stream>>>(cnt);
    hist_kernel<<<E_EDGES / 256, 256, 0, stream>>>(dstv, cnt);
    scan_kernel<<<1, 1024, 0, stream>>>(cnt, row_ptr, cursor, dinv);
    fill_kernel<<<E_EDGES / 256, 256, 0, stream>>>(srcv, dstv, cursor, csr_src);

    // ---- input splits ----
    split_kernel<<<(N_NODES * F_IN / 4) / 256, 256, 0, stream>>>(x, xh, xl, N_NODES * F_IN / 4);
    split_wt_kernel<<<(F_IN * H_DIM + 255) / 256, 256, 0, stream>>>(W1, w1th, w1tl, F_IN, H_DIM);
    split_wt_kernel<<<(H_DIM * O_DIM + 255) / 256, 256, 0, stream>>>(W2, w2th, w2tl, H_DIM, O_DIM);

    // ---- layer 1: g1 = dinv*(x@W1) ----
    {
        dim3 grid(H_DIM / 128, N_NODES / 128);
        gemm_mfma_kernel<H_DIM, F_IN><<<grid, 256, 0, stream>>>(xh, xl, w1th, w1tl, dinv, g1);
    }
    gather256_split_kernel<<<N_NODES / 4, 256, 0, stream>>>(g1, row_ptr, csr_src, dinv, b1, hh, hl);

    // ---- layer 2: g2 = dinv*(h@W2) ----
    {
        dim3 grid(O_DIM / 128, N_NODES / 128);
        gemm_mfma_kernel<O_DIM, H_DIM><<<grid, 256, 0, stream>>>(hh, hl, w2th, w2tl, dinv, g2);
    }
    gather128_kernel<<<N_NODES / 8, 256, 0, stream>>>(g2, row_ptr, csr_src, dinv, b2, z);

    // ---- head ----
    head_kernel<<<N_NODES, 128, 0, stream>>>(z, Wmu, bmu, Wlv, blv, eps, mu_out, lv_out, zrh, zrl);

    // ---- adjacency reconstruction ----
    {
        dim3 grid(N_NODES / 128, N_NODES / 128);
        adj_mfma_kernel<<<grid, 256, 0, stream>>>(zrh, zrl, out);
    }
}